// Round 4
// baseline (158.812 us; speedup 1.0000x reference)
//
#include <hip/hip_runtime.h>
#include <cstdint>
#include <cstddef>

typedef _Float16 f16;
typedef f16 f16x2 __attribute__((ext_vector_type(2)));
typedef f16 f16x4 __attribute__((ext_vector_type(4)));
typedef f16 f16x8 __attribute__((ext_vector_type(8)));
typedef float f32x4 __attribute__((ext_vector_type(4)));

// Global layouts for GEMM operands are CHUNK-SWIZZLED: within each 64-f16
// K-group of row r, the 8-f16 chunk c is stored at position c^(r&7).
// GEMM staging is then PURE IDENTITY (load offset == store offset == cid*8);
// fragment reads use the XOR formula (r7-proven conflict-free).

typedef __attribute__((address_space(3))) uint32_t lds_u32_t;
typedef __attribute__((address_space(1))) const uint32_t glb_u32_t;

__device__ __forceinline__ void gload_lds16(const f16* g, f16* l) {
  __builtin_amdgcn_global_load_lds((glb_u32_t*)(uintptr_t)g,
                                   (lds_u32_t*)(uint32_t)(uintptr_t)l,
                                   16, 0, 0);
}

// ---- prep: transposes (0..1023) then x cvt (1024..3071, 8 elems/thread) ----
__global__ __launch_bounds__(256) void k_prep(const float* __restrict__ x,
                                              const float* __restrict__ Wqkv,
                                              const float* __restrict__ Wproj,
                                              f16* __restrict__ Xh,
                                              f16* __restrict__ WqkvT,
                                              f16* __restrict__ WprojT) {
  const int bid = blockIdx.x, t = threadIdx.x;
  if (bid >= 1024) {
    int gid = (bid - 1024) * 256 + t;   // 0..524287
    int r = gid >> 7;                   // row 0..4095
    int c = gid & 127;                  // 8-f16 chunk in row
    int g = c >> 3, cl = c & 7;
    const float* src = x + ((size_t)r << 10) + c * 8;
    float4 u0 = *(const float4*)src;
    float4 u1 = *(const float4*)(src + 4);
    f16x8 hv;
    hv[0] = (f16)u0.x; hv[1] = (f16)u0.y; hv[2] = (f16)u0.z; hv[3] = (f16)u0.w;
    hv[4] = (f16)u1.x; hv[5] = (f16)u1.y; hv[6] = (f16)u1.z; hv[7] = (f16)u1.w;
    *(f16x8*)(Xh + ((size_t)r << 10) + g * 64 + ((cl ^ (r & 7)) * 8)) = hv;
    return;
  }
  const float* in;
  f16* out;
  int N, bx, by;
  if (bid < 768) {
    bx = bid % 48; by = bid / 48; in = Wqkv; out = WqkvT; N = 3072;
  } else {
    int tb = bid - 768;
    bx = tb % 16; by = tb / 16; in = Wproj; out = WprojT; N = 1024;
  }
  const int K = 1024;
  __shared__ float tile[64][65];
  const int xx = t & 63, y0 = t >> 6;
#pragma unroll
  for (int r = 0; r < 16; ++r) {
    int y = y0 + r * 4;
    tile[y][xx] = in[(size_t)(by * 64 + y) * N + bx * 64 + xx];
  }
  __syncthreads();
  const int ch = xx >> 3, off = xx & 7;
#pragma unroll
  for (int r = 0; r < 16; ++r) {
    int y = y0 + r * 4;
    int n = bx * 64 + y;
    out[(size_t)n * K + by * 64 + ((ch ^ (n & 7)) * 8) + off] =
        (f16)tile[xx][y];
  }
}

// ===================== 256x192 deep-pipelined GEMM (QKV) ====================
// 4 phases per K-tile (m201 granularity): phase p = {stage/frag ds_reads,
// barrier, lgkmcnt(0), 12 MFMA, barrier}. vmcnt(7) once per K-tile (end P1)
// forces tile t+1 landed before P2 reads B(t+1) fragments. A: 3 LDS bufs,
// B: 2 (144 KiB dynamic). XCD swizzle: 256 blocks = 8 XCD x 32.
__global__ __launch_bounds__(512, 1) void k_gemm256(const f16* __restrict__ A,
                                                    const f16* __restrict__ Bt,
                                                    f16* __restrict__ C,
                                                    int M, int N, int K) {
  extern __shared__ __align__(16) f16 sm[];
  const int t = threadIdx.x;
  const int bid = blockIdx.x;
  const int swz = (bid & 7) * 32 + (bid >> 3);             // 256 = 8 XCD x 32
  const int m0 = (swz & 15) * 256, n0 = (swz >> 4) * 192;
  const int w = t >> 6, l = t & 63, sl = l & 15, quad = l >> 4;
  const int wr = w >> 2, wc = w & 3;                       // 2 x 4 waves
  const f16* Ab = A + (size_t)m0 * K;
  const f16* Bb = Bt + (size_t)n0 * K;
  const int nk = K >> 6;                                   // 16
  f32x4 acc[8][3] = {};
  f16x8 bcur[3][2], bnext[3][2];

  auto abuf = [&](int buf) -> f16* { return sm + buf * 16384; };      // 3x
  auto bbuf = [&](int buf) -> f16* { return sm + 49152 + buf * 12288; }; // 2x

  auto stageA = [&](int kt, int buf) {
    f16* dst = abuf(buf);
#pragma unroll
    for (int c = 0; c < 4; ++c) {
      int cid = t + c * 512, row = cid >> 3;               // row 0..255
      gload_lds16(Ab + (size_t)row * K + kt * 64 + (cid & 7) * 8,
                  dst + cid * 8);
    }
  };
  auto stageB = [&](int kt, int buf) {
    f16* dst = bbuf(buf);
#pragma unroll
    for (int c = 0; c < 3; ++c) {
      int cid = t + c * 512, row = cid >> 3;               // row 0..191
      gload_lds16(Bb + (size_t)row * K + kt * 64 + (cid & 7) * 8,
                  dst + cid * 8);
    }
  };

  // ---- prologue: stage tiles 0,1; force tile0 landed; preload B(0) frags
  stageA(0, 0); stageB(0, 0);
  stageA(1, 1); stageB(1, 1);
  asm volatile("s_waitcnt vmcnt(7)" ::: "memory");   // oldest 7 = tile0's
  __builtin_amdgcn_sched_barrier(0);
  __builtin_amdgcn_s_barrier();
#pragma unroll
  for (int ni = 0; ni < 3; ++ni) {
    const int rb = wc * 48 + ni * 16 + sl;
#pragma unroll
    for (int kx = 0; kx < 2; ++kx)
      bcur[ni][kx] = *(const f16x8*)(bbuf(0) + rb * 64 +
                                     (((kx * 4 + quad) ^ (rb & 7)) * 8));
  }
  asm volatile("s_waitcnt lgkmcnt(0)" ::: "memory");
  __builtin_amdgcn_sched_barrier(0);
  __builtin_amdgcn_s_barrier();                      // B(0) reads retired

  int ba = 0;                                        // A buffer = kt % 3
  for (int kt = 0; kt < nk; ++kt) {
    const int bb = kt & 1;                           // B stage dest (t+2)
    const int ba2 = ba + 2 >= 3 ? ba - 1 : ba + 2;   // (kt+2) % 3
    const int ban = ba + 1 >= 3 ? 0 : ba + 1;        // (kt+1) % 3
    const bool hasS = kt + 2 < nk;
    const bool hasN = kt + 1 < nk;
    const f16* Abase = abuf(ba);
    f16x8 af[2][2];

    // -------- P0: stage A(t+2); read A mi{0,1}; MFMA mi{0,1} --------
    if (hasS) stageA(kt + 2, ba2);
#pragma unroll
    for (int mp = 0; mp < 2; ++mp) {
      const int ra = wr * 128 + mp * 16 + sl;
#pragma unroll
      for (int kx = 0; kx < 2; ++kx)
        af[mp][kx] = *(const f16x8*)(Abase + ra * 64 +
                                     (((kx * 4 + quad) ^ (ra & 7)) * 8));
    }
    __builtin_amdgcn_s_barrier();
    asm volatile("s_waitcnt lgkmcnt(0)" ::: "memory");
    __builtin_amdgcn_sched_barrier(0);
    __builtin_amdgcn_s_setprio(1);
#pragma unroll
    for (int mp = 0; mp < 2; ++mp)
#pragma unroll
      for (int ni = 0; ni < 3; ++ni)
#pragma unroll
        for (int kx = 0; kx < 2; ++kx)
          acc[mp][ni] = __builtin_amdgcn_mfma_f32_16x16x32_f16(
              af[mp][kx], bcur[ni][kx], acc[mp][ni], 0, 0, 0);
    __builtin_amdgcn_s_setprio(0);
    __builtin_amdgcn_s_barrier();

    // -------- P1: stage B(t+2); read A mi{2,3}; MFMA; vmcnt gate --------
    if (hasS) stageB(kt + 2, bb);
#pragma unroll
    for (int mp = 0; mp < 2; ++mp) {
      const int ra = wr * 128 + (2 + mp) * 16 + sl;
#pragma unroll
      for (int kx = 0; kx < 2; ++kx)
        af[mp][kx] = *(const f16x8*)(Abase + ra * 64 +
                                     (((kx * 4 + quad) ^ (ra & 7)) * 8));
    }
    __builtin_amdgcn_s_barrier();
    asm volatile("s_waitcnt lgkmcnt(0)" ::: "memory");
    __builtin_amdgcn_sched_barrier(0);
    __builtin_amdgcn_s_setprio(1);
#pragma unroll
    for (int mp = 0; mp < 2; ++mp)
#pragma unroll
      for (int ni = 0; ni < 3; ++ni)
#pragma unroll
        for (int kx = 0; kx < 2; ++kx)
          acc[2 + mp][ni] = __builtin_amdgcn_mfma_f32_16x16x32_f16(
              af[mp][kx], bcur[ni][kx], acc[2 + mp][ni], 0, 0, 0);
    __builtin_amdgcn_s_setprio(0);
    if (hasS)
      asm volatile("s_waitcnt vmcnt(7)" ::: "memory");  // forces tile t+1
    else
      asm volatile("s_waitcnt vmcnt(0)" ::: "memory");  // tail drain
    __builtin_amdgcn_sched_barrier(0);
    __builtin_amdgcn_s_barrier();                       // t+1 LDS visible

    // -------- P2: read A mi{4,5} + B(t+1) ni{0,1}; MFMA mi{4,5} --------
#pragma unroll
    for (int mp = 0; mp < 2; ++mp) {
      const int ra = wr * 128 + (4 + mp) * 16 + sl;
#pragma unroll
      for (int kx = 0; kx < 2; ++kx)
        af[mp][kx] = *(const f16x8*)(Abase + ra * 64 +
                                     (((kx * 4 + quad) ^ (ra & 7)) * 8));
    }
    if (hasN) {
#pragma unroll
      for (int ni = 0; ni < 2; ++ni) {
        const int rb = wc * 48 + ni * 16 + sl;
#pragma unroll
        for (int kx = 0; kx < 2; ++kx)
          bnext[ni][kx] = *(const f16x8*)(bbuf((kt + 1) & 1) + rb * 64 +
                                          (((kx * 4 + quad) ^ (rb & 7)) * 8));
      }
    }
    __builtin_amdgcn_s_barrier();
    asm volatile("s_waitcnt lgkmcnt(0)" ::: "memory");
    __builtin_amdgcn_sched_barrier(0);
    __builtin_amdgcn_s_setprio(1);
#pragma unroll
    for (int mp = 0; mp < 2; ++mp)
#pragma unroll
      for (int ni = 0; ni < 3; ++ni)
#pragma unroll
        for (int kx = 0; kx < 2; ++kx)
          acc[4 + mp][ni] = __builtin_amdgcn_mfma_f32_16x16x32_f16(
              af[mp][kx], bcur[ni][kx], acc[4 + mp][ni], 0, 0, 0);
    __builtin_amdgcn_s_setprio(0);
    __builtin_amdgcn_s_barrier();

    // -------- P3: read A mi{6,7} + B(t+1) ni{2}; MFMA mi{6,7} --------
#pragma unroll
    for (int mp = 0; mp < 2; ++mp) {
      const int ra = wr * 128 + (6 + mp) * 16 + sl;
#pragma unroll
      for (int kx = 0; kx < 2; ++kx)
        af[mp][kx] = *(const f16x8*)(Abase + ra * 64 +
                                     (((kx * 4 + quad) ^ (ra & 7)) * 8));
    }
    if (hasN) {
      const int rb = wc * 48 + 2 * 16 + sl;
#pragma unroll
      for (int kx = 0; kx < 2; ++kx)
        bnext[2][kx] = *(const f16x8*)(bbuf((kt + 1) & 1) + rb * 64 +
                                       (((kx * 4 + quad) ^ (rb & 7)) * 8));
    }
    __builtin_amdgcn_s_barrier();
    asm volatile("s_waitcnt lgkmcnt(0)" ::: "memory");
    __builtin_amdgcn_sched_barrier(0);
    __builtin_amdgcn_s_setprio(1);
#pragma unroll
    for (int mp = 0; mp < 2; ++mp)
#pragma unroll
      for (int ni = 0; ni < 3; ++ni)
#pragma unroll
        for (int kx = 0; kx < 2; ++kx)
          acc[6 + mp][ni] = __builtin_amdgcn_mfma_f32_16x16x32_f16(
              af[mp][kx], bcur[ni][kx], acc[6 + mp][ni], 0, 0, 0);
    __builtin_amdgcn_s_setprio(0);
    __builtin_amdgcn_s_barrier();   // A(t)/B(t) reads retired: restage-safe

    if (hasN) {
#pragma unroll
      for (int ni = 0; ni < 3; ++ni)
#pragma unroll
        for (int kx = 0; kx < 2; ++kx)
          bcur[ni][kx] = bnext[ni][kx];
    }
    ba = ban;
  }
  // ---- epilogue: C write (f16) ----
#pragma unroll
  for (int mi = 0; mi < 8; ++mi)
#pragma unroll
    for (int ni = 0; ni < 3; ++ni) {
      const int row = m0 + wr * 128 + mi * 16 + quad * 4;
      const int col = n0 + wc * 48 + ni * 16 + sl;
#pragma unroll
      for (int r = 0; r < 4; ++r)
        C[(size_t)(row + r) * N + col] = (f16)acc[mi][ni][r];
    }
}

// ------------- GEMM: C[M][N] = A[M][K] * Bt[N][K]^T  (f16 in, fp32 acc) ----
// (m97 structure; used for the proj GEMM where a 256-wide tile would leave
// most of the chip idle: grid 32x8 = 256 blocks fills all CUs.)
template <int F32OUT>
__global__ __launch_bounds__(256) void k_gemm_bt(const f16* __restrict__ A,
                                                 const f16* __restrict__ Bt,
                                                 void* __restrict__ Cout,
                                                 int M, int N, int K) {
  __shared__ __align__(16) f16 As[128 * 64];
  __shared__ __align__(16) f16 Bs[128 * 64];
  const int t = threadIdx.x;
  const int m0 = blockIdx.x * 128, n0 = blockIdx.y * 128;
  const int w = t >> 6, l = t & 63, sl = l & 15, quad = l >> 4;
  const int wm = (w & 1) * 64, wn = (w >> 1) * 64;
  f32x4 acc[4][4] = {};
  const int nk = K >> 6;
  const f16* Ab = A + (size_t)m0 * K;
  const f16* Bb = Bt + (size_t)n0 * K;
  for (int kt = 0; kt < nk; ++kt) {
    __syncthreads();
#pragma unroll
    for (int c = 0; c < 4; ++c) {
      int cid = t + c * 256;          // 0..1023
      int row = cid >> 3;             // 0..127
      int o8 = cid * 8 - row * 64;    // = (cid&7)*8
      gload_lds16(Ab + (size_t)row * K + kt * 64 + o8, As + cid * 8);
      gload_lds16(Bb + (size_t)row * K + kt * 64 + o8, Bs + cid * 8);
    }
    __syncthreads();
#pragma unroll
    for (int kk = 0; kk < 64; kk += 32) {
      const int cb = kk >> 3;
      f16x8 af[4], bfr[4];
#pragma unroll
      for (int mi = 0; mi < 4; ++mi)
        af[mi] = *(const f16x8*)(As + (wm + mi * 16 + sl) * 64 +
                                 (((cb + quad) ^ (sl & 7)) * 8));
#pragma unroll
      for (int ni = 0; ni < 4; ++ni)
        bfr[ni] = *(const f16x8*)(Bs + (wn + ni * 16 + sl) * 64 +
                                  (((cb + quad) ^ (sl & 7)) * 8));
#pragma unroll
      for (int mi = 0; mi < 4; ++mi)
#pragma unroll
        for (int ni = 0; ni < 4; ++ni)
          acc[mi][ni] = __builtin_amdgcn_mfma_f32_16x16x32_f16(
              af[mi], bfr[ni], acc[mi][ni], 0, 0, 0);
    }
  }
#pragma unroll
  for (int mi = 0; mi < 4; ++mi)
#pragma unroll
    for (int ni = 0; ni < 4; ++ni) {
      int row = m0 + wm + mi * 16 + quad * 4;
      int col = n0 + wn + ni * 16 + sl;
#pragma unroll
      for (int r = 0; r < 4; ++r) {
        if (F32OUT)
          ((float*)Cout)[(size_t)(row + r) * N + col] = acc[mi][ni][r];
        else
          ((f16*)Cout)[(size_t)(row + r) * N + col] = (f16)acc[mi][ni][r];
      }
    }
}

// ---------------- MFMA sparse flash attention (r12 version) ----------------
__global__ __launch_bounds__(256) void k_attn(const f16* __restrict__ qkv,
                                              f16* __restrict__ y) {
  constexpr int VT = 226;
  constexpr int KT = 72;
  constexpr int PT = 232;
  __shared__ __align__(16) char smem[224 * KT * 2 + 4 * 16 * PT * 2 + 512];
  f16* Ks = (f16*)smem;
  f16* Vt = (f16*)smem;                  // aliases Ks (phase 3+)
  f16* Pb = (f16*)(smem + 224 * KT * 2);
  float* rmax = (float*)(smem + 224 * KT * 2 + 4 * 16 * PT * 2);
  float* lsum = rmax + 64;

  const int t = threadIdx.x, wv = t >> 6, l = t & 63;
  const int sl = l & 15, quad = l >> 4;
  const int blk = blockIdx.x;
  const int qb = blk & 31;
  const int bh = blk >> 5;
  const int b = bh >> 4, h = bh & 15;
  const f16* base = qkv + (size_t)b * 2048 * 3072;
  const int qc = h * 64, kc = 1024 + h * 64, vc = 2048 + h * 64;

  const int row0 = qb * 64;
  const int hi = row0 + 63;
  int lo = row0 - 127; if (lo < 0) lo = 0;
  const int ng = (lo + 63) >> 6;
  const int T = ng + (hi - lo + 1);
  int NT = (T + 15) >> 4;
  NT = (NT + 1) & ~1;
  const int NC = NT * 16;

  for (int cid = t; cid < NC * 8; cid += 256) {
    int idx = cid >> 3, ch = cid & 7;
    int j = idx < ng ? idx * 64 : lo + idx - ng;
    if (idx >= T) j = lo;
    *(uint4*)(Ks + idx * KT + ch * 8) =
        *(const uint4*)(base + (size_t)j * 3072 + kc + ch * 8);
  }
  const int i0 = row0 + wv * 16;
  f16x8 aq[2];
#pragma unroll
  for (int c = 0; c < 2; ++c) {
    f16x8 qv = *(const f16x8*)(base + (size_t)(i0 + sl) * 3072 + qc + c * 32 +
                               quad * 8);
#pragma unroll
    for (int jj = 0; jj < 8; ++jj) qv[jj] = qv[jj] * (f16)0.125f;
    aq[c] = qv;
  }
  __syncthreads();

  f16* Pw = Pb + wv * 16 * PT;
  float mloc[4] = {-INFINITY, -INFINITY, -INFINITY, -INFINITY};
  for (int kt = 0; kt < NT; ++kt) {
    const int idx = kt * 16 + sl;
    const bool pad = idx >= T;
    int j = idx < ng ? idx * 64 : lo + idx - ng;
    if (pad) j = lo;
    const f16* krow = Ks + idx * KT;
    f16x8 bk0 = *(const f16x8*)(krow + quad * 8);
    f16x8 bk1 = *(const f16x8*)(krow + 32 + quad * 8);
    f32x4 s = {0.f, 0.f, 0.f, 0.f};
    s = __builtin_amdgcn_mfma_f32_16x16x32_f16(aq[0], bk0, s, 0, 0, 0);
    s = __builtin_amdgcn_mfma_f32_16x16x32_f16(aq[1], bk1, s, 0, 0, 0);
#pragma unroll
    for (int r = 0; r < 4; ++r) {
      const int i = i0 + quad * 4 + r;
      const bool ok = !pad && (j <= i) && ((i - j) < 128 || (j & 63) == 0);
      const float sv = ok ? s[r] : -INFINITY;
      mloc[r] = fmaxf(mloc[r], sv);
      Pw[(quad * 4 + r) * PT + idx] = (f16)sv;
    }
  }
#pragma unroll
  for (int off = 1; off < 16; off <<= 1)
#pragma unroll
    for (int r = 0; r < 4; ++r)
      mloc[r] = fmaxf(mloc[r], __shfl_xor(mloc[r], off, 64));
  if (sl == 0)
#pragma unroll
    for (int r = 0; r < 4; ++r) rmax[wv * 16 + quad * 4 + r] = mloc[r];
  __syncthreads();

  for (int cid = t; cid < NC * 8; cid += 256) {
    int idx = cid >> 3, ch = cid & 7;
    int j = idx < ng ? idx * 64 : lo + idx - ng;
    if (idx >= T) j = lo;
    f16x8 v8 = *(const f16x8*)(base + (size_t)j * 3072 + vc + ch * 8);
#pragma unroll
    for (int jj = 0; jj < 8; ++jj) Vt[(ch * 8 + jj) * VT + idx] = v8[jj];
  }
  __syncthreads();

  const int NKC = NC / 32;
  f32x4 o[4] = {};
  float ls = 0.f;
  const float mrow = rmax[wv * 16 + sl];
  for (int kcc = 0; kcc < NKC; ++kcc) {
    f16x8 raw = *(const f16x8*)(Pw + sl * PT + kcc * 32 + quad * 8);
    f16x8 ap;
#pragma unroll
    for (int jj = 0; jj < 8; ++jj) {
      float p = __expf((float)raw[jj] - mrow);
      ls += p;
      ap[jj] = (f16)p;
    }
#pragma unroll
    for (int dt = 0; dt < 4; ++dt) {
      const uint32_t* vb =
          (const uint32_t*)(Vt + (dt * 16 + sl) * VT + kcc * 32 + quad * 8);
      union { uint32_t u[4]; f16x8 v; } cv;
      cv.u[0] = vb[0]; cv.u[1] = vb[1]; cv.u[2] = vb[2]; cv.u[3] = vb[3];
      o[dt] = __builtin_amdgcn_mfma_f32_16x16x32_f16(ap, cv.v, o[dt], 0, 0, 0);
    }
  }
  ls += __shfl_xor(ls, 16, 64);
  ls += __shfl_xor(ls, 32, 64);
  if (quad == 0) lsum[wv * 16 + sl] = ls;
  __syncthreads();
#pragma unroll
  for (int r = 0; r < 4; ++r) {
    const int q = quad * 4 + r;
    const float inv = 1.0f / lsum[wv * 16 + q];
    const int grow = i0 + q;
    const int sw = grow & 7;
    f16* yr = y + (((size_t)b * 2048 + grow) << 10) + h * 64;
    const int off = sl & 7, cbase = sl >> 3;
#pragma unroll
    for (int dt = 0; dt < 4; ++dt) {
      int cg = dt * 2 + cbase;
      yr[((cg ^ sw) * 8) + off] = (f16)(o[dt][r] * inv);
    }
  }
}

extern "C" void kernel_launch(void* const* d_in, const int* in_sizes, int n_in,
                              void* d_out, int out_size, void* d_ws,
                              size_t ws_size, hipStream_t stream) {
  (void)in_sizes; (void)n_in; (void)out_size; (void)ws_size;
  const float* x = (const float*)d_in[0];
  const float* Wqkv = (const float*)d_in[1];
  const float* Wproj = (const float*)d_in[2];
  float* out = (float*)d_out;
  char* ws = (char*)d_ws;
  f16* Xh     = (f16*)(ws);                         // 4096x1024 (swizzled)
  f16* WqkvT  = (f16*)(ws + (size_t)8  * 1048576);  // 3072x1024 (swizzled)
  f16* WprojT = (f16*)(ws + (size_t)14 * 1048576);  // 1024x1024 (swizzled)
  f16* QKV    = (f16*)(ws + (size_t)16 * 1048576);  // 4096x3072 (normal)
  f16* Yh     = (f16*)(ws + (size_t)40 * 1048576);  // 4096x1024 (swizzled)

  static bool attr_done = false;
  if (!attr_done) {
    (void)hipFuncSetAttribute((const void*)k_gemm256,
                              hipFuncAttributeMaxDynamicSharedMemorySize,
                              147456);
    attr_done = true;
  }

  k_prep<<<3072, 256, 0, stream>>>(x, Wqkv, Wproj, Xh, WqkvT, WprojT);
  k_gemm256<<<256, 512, 147456, stream>>>(Xh, WqkvT, QKV, 4096, 3072, 1024);
  k_attn<<<1024, 256, 0, stream>>>(QKV, Yh);
  k_gemm_bt<1><<<dim3(32, 8), 256, 0, stream>>>(Yh, WprojT, (void*)out, 4096,
                                                1024, 1024);
}

// Round 5
// 157.516 us; speedup vs baseline: 1.0082x; 1.0082x over previous
//
#include <hip/hip_runtime.h>
#include <cstdint>
#include <cstddef>

typedef _Float16 f16;
typedef f16 f16x2 __attribute__((ext_vector_type(2)));
typedef f16 f16x4 __attribute__((ext_vector_type(4)));
typedef f16 f16x8 __attribute__((ext_vector_type(8)));
typedef float f32x4 __attribute__((ext_vector_type(4)));

// Global layouts for GEMM operands are CHUNK-SWIZZLED: within each 64-f16
// K-group of row r, the 8-f16 chunk c is stored at position c^(r&7).
// GEMM staging is then PURE IDENTITY (load offset == store offset == cid*8);
// fragment reads use the XOR formula (r7-proven conflict-free).

typedef __attribute__((address_space(3))) uint32_t lds_u32_t;
typedef __attribute__((address_space(1))) const uint32_t glb_u32_t;

__device__ __forceinline__ void gload_lds16(const f16* g, f16* l) {
  __builtin_amdgcn_global_load_lds((glb_u32_t*)(uintptr_t)g,
                                   (lds_u32_t*)(uint32_t)(uintptr_t)l,
                                   16, 0, 0);
}

// ---- prep: transposes (0..1023) then x cvt (1024..3071, 8 elems/thread) ----
__global__ __launch_bounds__(256) void k_prep(const float* __restrict__ x,
                                              const float* __restrict__ Wqkv,
                                              const float* __restrict__ Wproj,
                                              f16* __restrict__ Xh,
                                              f16* __restrict__ WqkvT,
                                              f16* __restrict__ WprojT) {
  const int bid = blockIdx.x, t = threadIdx.x;
  if (bid >= 1024) {
    int gid = (bid - 1024) * 256 + t;   // 0..524287
    int r = gid >> 7;                   // row 0..4095
    int c = gid & 127;                  // 8-f16 chunk in row
    int g = c >> 3, cl = c & 7;
    const float* src = x + ((size_t)r << 10) + c * 8;
    float4 u0 = *(const float4*)src;
    float4 u1 = *(const float4*)(src + 4);
    f16x8 hv;
    hv[0] = (f16)u0.x; hv[1] = (f16)u0.y; hv[2] = (f16)u0.z; hv[3] = (f16)u0.w;
    hv[4] = (f16)u1.x; hv[5] = (f16)u1.y; hv[6] = (f16)u1.z; hv[7] = (f16)u1.w;
    *(f16x8*)(Xh + ((size_t)r << 10) + g * 64 + ((cl ^ (r & 7)) * 8)) = hv;
    return;
  }
  const float* in;
  f16* out;
  int N, bx, by;
  if (bid < 768) {
    bx = bid % 48; by = bid / 48; in = Wqkv; out = WqkvT; N = 3072;
  } else {
    int tb = bid - 768;
    bx = tb % 16; by = tb / 16; in = Wproj; out = WprojT; N = 1024;
  }
  const int K = 1024;
  __shared__ float tile[64][65];
  const int xx = t & 63, y0 = t >> 6;
#pragma unroll
  for (int r = 0; r < 16; ++r) {
    int y = y0 + r * 4;
    tile[y][xx] = in[(size_t)(by * 64 + y) * N + bx * 64 + xx];
  }
  __syncthreads();
  const int ch = xx >> 3, off = xx & 7;
#pragma unroll
  for (int r = 0; r < 16; ++r) {
    int y = y0 + r * 4;
    int n = bx * 64 + y;
    out[(size_t)n * K + by * 64 + ((ch ^ (n & 7)) * 8) + off] =
        (f16)tile[xx][y];
  }
}

// ===================== 256x192 deep-pipelined GEMM (QKV) ====================
// r3-proven 2-phase schedule (4-phase variant regressed: barrier overhead at
// 1 block/CU). Counted-vmcnt pipeline: stages for tile t+2 issued at tile t,
// vmcnt(7) forces tile t+1 landed; never drain-0 in steady state.
__global__ __launch_bounds__(512, 1) void k_gemm256(const f16* __restrict__ A,
                                                    const f16* __restrict__ Bt,
                                                    f16* __restrict__ C,
                                                    int M, int N, int K) {
  extern __shared__ __align__(16) f16 sm[];
  const int t = threadIdx.x;
  const int bid = blockIdx.x;
  const int swz = (bid & 7) * 32 + (bid >> 3);             // 256 = 8 XCD x 32
  const int m0 = (swz & 15) * 256, n0 = (swz >> 4) * 192;
  const int w = t >> 6, l = t & 63, sl = l & 15, quad = l >> 4;
  const int wr = w >> 2, wc = w & 3;                       // 2 x 4 waves
  const f16* Ab = A + (size_t)m0 * K;
  const f16* Bb = Bt + (size_t)n0 * K;
  const int nk = K >> 6;                                   // 16
  f32x4 acc[8][3] = {};
  f16x8 bcur[3][2], bnext[3][2];

  auto abuf = [&](int buf) -> f16* { return sm + buf * 16384; };      // 3x
  auto bbuf = [&](int buf) -> f16* { return sm + 49152 + buf * 12288; }; // 2x

  auto stageA = [&](int kt, int buf) {
    f16* dst = abuf(buf);
#pragma unroll
    for (int c = 0; c < 4; ++c) {
      int cid = t + c * 512, row = cid >> 3;               // row 0..255
      gload_lds16(Ab + (size_t)row * K + kt * 64 + (cid & 7) * 8,
                  dst + cid * 8);
    }
  };
  auto stageB = [&](int kt, int buf) {
    f16* dst = bbuf(buf);
#pragma unroll
    for (int c = 0; c < 3; ++c) {
      int cid = t + c * 512, row = cid >> 3;               // row 0..191
      gload_lds16(Bb + (size_t)row * K + kt * 64 + (cid & 7) * 8,
                  dst + cid * 8);
    }
  };

  // ---- prologue: stage tiles 0,1; force tile0 landed; preload B(0) frags
  stageA(0, 0); stageB(0, 0);
  stageA(1, 1); stageB(1, 1);
  asm volatile("s_waitcnt vmcnt(7)" ::: "memory");   // oldest 7 = tile0's
  __builtin_amdgcn_sched_barrier(0);
  __builtin_amdgcn_s_barrier();
#pragma unroll
  for (int ni = 0; ni < 3; ++ni) {
    const int rb = wc * 48 + ni * 16 + sl;
#pragma unroll
    for (int kx = 0; kx < 2; ++kx)
      bcur[ni][kx] = *(const f16x8*)(bbuf(0) + rb * 64 +
                                     (((kx * 4 + quad) ^ (rb & 7)) * 8));
  }
  asm volatile("s_waitcnt lgkmcnt(0)" ::: "memory");
  __builtin_amdgcn_sched_barrier(0);
  __builtin_amdgcn_s_barrier();                      // B(0) reads retired

  int ba = 0;                                        // A buffer = kt % 3
  for (int kt = 0; kt < nk; ++kt) {
    const int bb = kt & 1;
    const int ba2 = ba + 2 >= 3 ? ba - 1 : ba + 2;   // (kt+2) % 3
    const int ban = ba + 1 >= 3 ? 0 : ba + 1;        // (kt+1) % 3
    // ---------------- PH1: stage t+2, JIT A0-3, MFMA mi0-3 ----------------
    if (kt + 2 < nk) { stageA(kt + 2, ba2); stageB(kt + 2, bb); }
    f16x8 afl[4][2];
#pragma unroll
    for (int mi = 0; mi < 4; ++mi) {
      const int ra = wr * 128 + mi * 16 + sl;
#pragma unroll
      for (int kx = 0; kx < 2; ++kx)
        afl[mi][kx] = *(const f16x8*)(abuf(ba) + ra * 64 +
                                      (((kx * 4 + quad) ^ (ra & 7)) * 8));
    }
    __builtin_amdgcn_s_setprio(1);
#pragma unroll
    for (int mi = 0; mi < 4; ++mi)
#pragma unroll
      for (int ni = 0; ni < 3; ++ni)
#pragma unroll
        for (int kx = 0; kx < 2; ++kx)
          acc[mi][ni] = __builtin_amdgcn_mfma_f32_16x16x32_f16(
              afl[mi][kx], bcur[ni][kx], acc[mi][ni], 0, 0, 0);
    __builtin_amdgcn_s_setprio(0);
    if (kt + 2 < nk)
      asm volatile("s_waitcnt vmcnt(7)" ::: "memory");  // forces tile t+1
    else
      asm volatile("s_waitcnt vmcnt(0)" ::: "memory");  // tail: drain
    __builtin_amdgcn_sched_barrier(0);
    __builtin_amdgcn_s_barrier();
    // ------------- PH2: A4-7 + B(t+1) reads, MFMA mi4-7, WAR fence --------
    f16x8 afh[4][2];
#pragma unroll
    for (int mi = 0; mi < 4; ++mi) {
      const int ra = wr * 128 + (mi + 4) * 16 + sl;
#pragma unroll
      for (int kx = 0; kx < 2; ++kx)
        afh[mi][kx] = *(const f16x8*)(abuf(ba) + ra * 64 +
                                      (((kx * 4 + quad) ^ (ra & 7)) * 8));
    }
    if (kt + 1 < nk) {
#pragma unroll
      for (int ni = 0; ni < 3; ++ni) {
        const int rb = wc * 48 + ni * 16 + sl;
#pragma unroll
        for (int kx = 0; kx < 2; ++kx)
          bnext[ni][kx] = *(const f16x8*)(bbuf((kt + 1) & 1) + rb * 64 +
                                          (((kx * 4 + quad) ^ (rb & 7)) * 8));
      }
    }
    __builtin_amdgcn_s_setprio(1);
#pragma unroll
    for (int mi = 0; mi < 4; ++mi)
#pragma unroll
      for (int ni = 0; ni < 3; ++ni)
#pragma unroll
        for (int kx = 0; kx < 2; ++kx)
          acc[mi + 4][ni] = __builtin_amdgcn_mfma_f32_16x16x32_f16(
              afh[mi][kx], bcur[ni][kx], acc[mi + 4][ni], 0, 0, 0);
    __builtin_amdgcn_s_setprio(0);
    asm volatile("s_waitcnt lgkmcnt(0)" ::: "memory");  // all reads retired
    __builtin_amdgcn_sched_barrier(0);
    __builtin_amdgcn_s_barrier();                       // restage-safe
#pragma unroll
    for (int ni = 0; ni < 3; ++ni)
#pragma unroll
      for (int kx = 0; kx < 2; ++kx)
        bcur[ni][kx] = bnext[ni][kx];
    ba = ban;
  }
  // ---- epilogue: C write (f16) ----
#pragma unroll
  for (int mi = 0; mi < 8; ++mi)
#pragma unroll
    for (int ni = 0; ni < 3; ++ni) {
      const int row = m0 + wr * 128 + mi * 16 + quad * 4;
      const int col = n0 + wc * 48 + ni * 16 + sl;
#pragma unroll
      for (int r = 0; r < 4; ++r)
        C[(size_t)(row + r) * N + col] = (f16)acc[mi][ni][r];
    }
}

// ------------- GEMM: C[M][N] = A[M][K] * Bt[N][K]^T  (f16 in, fp32 acc) ----
template <int F32OUT>
__global__ __launch_bounds__(256) void k_gemm_bt(const f16* __restrict__ A,
                                                 const f16* __restrict__ Bt,
                                                 void* __restrict__ Cout,
                                                 int M, int N, int K) {
  __shared__ __align__(16) f16 As[128 * 64];
  __shared__ __align__(16) f16 Bs[128 * 64];
  const int t = threadIdx.x;
  const int m0 = blockIdx.x * 128, n0 = blockIdx.y * 128;
  const int w = t >> 6, l = t & 63, sl = l & 15, quad = l >> 4;
  const int wm = (w & 1) * 64, wn = (w >> 1) * 64;
  f32x4 acc[4][4] = {};
  const int nk = K >> 6;
  const f16* Ab = A + (size_t)m0 * K;
  const f16* Bb = Bt + (size_t)n0 * K;
  for (int kt = 0; kt < nk; ++kt) {
    __syncthreads();
#pragma unroll
    for (int c = 0; c < 4; ++c) {
      int cid = t + c * 256;          // 0..1023
      int row = cid >> 3;             // 0..127
      int o8 = cid * 8 - row * 64;    // = (cid&7)*8
      gload_lds16(Ab + (size_t)row * K + kt * 64 + o8, As + cid * 8);
      gload_lds16(Bb + (size_t)row * K + kt * 64 + o8, Bs + cid * 8);
    }
    __syncthreads();
#pragma unroll
    for (int kk = 0; kk < 64; kk += 32) {
      const int cb = kk >> 3;
      f16x8 af[4], bfr[4];
#pragma unroll
      for (int mi = 0; mi < 4; ++mi)
        af[mi] = *(const f16x8*)(As + (wm + mi * 16 + sl) * 64 +
                                 (((cb + quad) ^ (sl & 7)) * 8));
#pragma unroll
      for (int ni = 0; ni < 4; ++ni)
        bfr[ni] = *(const f16x8*)(Bs + (wn + ni * 16 + sl) * 64 +
                                  (((cb + quad) ^ (sl & 7)) * 8));
#pragma unroll
      for (int mi = 0; mi < 4; ++mi)
#pragma unroll
        for (int ni = 0; ni < 4; ++ni)
          acc[mi][ni] = __builtin_amdgcn_mfma_f32_16x16x32_f16(
              af[mi], bfr[ni], acc[mi][ni], 0, 0, 0);
    }
  }
#pragma unroll
  for (int mi = 0; mi < 4; ++mi)
#pragma unroll
    for (int ni = 0; ni < 4; ++ni) {
      int row = m0 + wm + mi * 16 + quad * 4;
      int col = n0 + wn + ni * 16 + sl;
#pragma unroll
      for (int r = 0; r < 4; ++r) {
        if (F32OUT)
          ((float*)Cout)[(size_t)(row + r) * N + col] = acc[mi][ni][r];
        else
          ((f16*)Cout)[(size_t)(row + r) * N + col] = (f16)acc[mi][ni][r];
      }
    }
}

// ---------------- MFMA sparse flash attention ----------------
// r5 changes vs r12 baseline: (1) V global loads hoisted before QK (latency
// hides under QK compute; statically-indexed vr[7] to stay in registers);
// (2) QK loop software-pipelined (prefetch next K frags over current MFMA+
// mask); (3) PV loop prefetches next P row over current exp+MFMA.
__global__ __launch_bounds__(256) void k_attn(const f16* __restrict__ qkv,
                                              f16* __restrict__ y) {
  constexpr int VT = 226;
  constexpr int KT = 72;
  constexpr int PT = 232;
  __shared__ __align__(16) char smem[224 * KT * 2 + 4 * 16 * PT * 2 + 512];
  f16* Ks = (f16*)smem;
  f16* Vt = (f16*)smem;                  // aliases Ks (phase 3+)
  f16* Pb = (f16*)(smem + 224 * KT * 2);
  float* rmax = (float*)(smem + 224 * KT * 2 + 4 * 16 * PT * 2);
  float* lsum = rmax + 64;

  const int t = threadIdx.x, wv = t >> 6, l = t & 63;
  const int sl = l & 15, quad = l >> 4;
  const int blk = blockIdx.x;
  const int qb = blk & 31;
  const int bh = blk >> 5;
  const int b = bh >> 4, h = bh & 15;
  const f16* base = qkv + (size_t)b * 2048 * 3072;
  const int qc = h * 64, kc = 1024 + h * 64, vc = 2048 + h * 64;

  const int row0 = qb * 64;
  const int hi = row0 + 63;
  int lo = row0 - 127; if (lo < 0) lo = 0;
  const int ng = (lo + 63) >> 6;
  const int T = ng + (hi - lo + 1);
  int NT = (T + 15) >> 4;
  NT = (NT + 1) & ~1;
  const int NC = NT * 16;

  // K stage: global -> LDS (row-major, padded KT)
  for (int cid = t; cid < NC * 8; cid += 256) {
    int idx = cid >> 3, ch = cid & 7;
    int j = idx < ng ? idx * 64 : lo + idx - ng;
    if (idx >= T) j = lo;
    *(uint4*)(Ks + idx * KT + ch * 8) =
        *(const uint4*)(base + (size_t)j * 3072 + kc + ch * 8);
  }
  // V loads hoisted (T14): issue now; LDS transpose-writes after QK barrier.
  // Statically indexed -> stays in VGPRs (28 regs). Inactive slots load row
  // lo (valid, L2-broadcast) to keep the unroll static.
  uint4 vr[7];
#pragma unroll
  for (int c = 0; c < 7; ++c) {
    int cid = t + c * 256;
    int idx = cid >> 3, ch = cid & 7;
    int j = idx < ng ? idx * 64 : lo + idx - ng;
    if (idx >= T) j = lo;
    vr[c] = *(const uint4*)(base + (size_t)j * 3072 + vc + ch * 8);
  }
  const int i0 = row0 + wv * 16;
  f16x8 aq[2];
#pragma unroll
  for (int c = 0; c < 2; ++c) {
    f16x8 qv = *(const f16x8*)(base + (size_t)(i0 + sl) * 3072 + qc + c * 32 +
                               quad * 8);
#pragma unroll
    for (int jj = 0; jj < 8; ++jj) qv[jj] = qv[jj] * (f16)0.125f;
    aq[c] = qv;
  }
  __syncthreads();

  f16* Pw = Pb + wv * 16 * PT;
  float mloc[4] = {-INFINITY, -INFINITY, -INFINITY, -INFINITY};
  // QK loop, software-pipelined: K frags for kt+1 load during kt's MFMA+mask.
  const f16* krow0 = Ks + sl * KT;
  f16x8 nbk0 = *(const f16x8*)(krow0 + quad * 8);
  f16x8 nbk1 = *(const f16x8*)(krow0 + 32 + quad * 8);
  for (int kt = 0; kt < NT; ++kt) {
    const int idx = kt * 16 + sl;
    f16x8 bk0 = nbk0, bk1 = nbk1;
    if (kt + 1 < NT) {
      const f16* kr2 = Ks + (idx + 16) * KT;
      nbk0 = *(const f16x8*)(kr2 + quad * 8);
      nbk1 = *(const f16x8*)(kr2 + 32 + quad * 8);
    }
    const bool pad = idx >= T;
    int j = idx < ng ? idx * 64 : lo + idx - ng;
    if (pad) j = lo;
    f32x4 s = {0.f, 0.f, 0.f, 0.f};
    s = __builtin_amdgcn_mfma_f32_16x16x32_f16(aq[0], bk0, s, 0, 0, 0);
    s = __builtin_amdgcn_mfma_f32_16x16x32_f16(aq[1], bk1, s, 0, 0, 0);
#pragma unroll
    for (int r = 0; r < 4; ++r) {
      const int i = i0 + quad * 4 + r;
      const bool ok = !pad && (j <= i) && ((i - j) < 128 || (j & 63) == 0);
      const float sv = ok ? s[r] : -INFINITY;
      mloc[r] = fmaxf(mloc[r], sv);
      Pw[(quad * 4 + r) * PT + idx] = (f16)sv;
    }
  }
#pragma unroll
  for (int off = 1; off < 16; off <<= 1)
#pragma unroll
    for (int r = 0; r < 4; ++r)
      mloc[r] = fmaxf(mloc[r], __shfl_xor(mloc[r], off, 64));
  if (sl == 0)
#pragma unroll
    for (int r = 0; r < 4; ++r) rmax[wv * 16 + quad * 4 + r] = mloc[r];
  __syncthreads();   // all Ks reads retired -> safe to overwrite with Vt

  // V transpose-writes from the pre-loaded registers.
#pragma unroll
  for (int c = 0; c < 7; ++c) {
    int cid = t + c * 256;
    if (cid < NC * 8) {
      int idx = cid >> 3, ch = cid & 7;
      const f16* pv = (const f16*)&vr[c];
#pragma unroll
      for (int jj = 0; jj < 8; ++jj) Vt[(ch * 8 + jj) * VT + idx] = pv[jj];
    }
  }
  __syncthreads();

  const int NKC = NC / 32;
  f32x4 o[4] = {};
  float ls = 0.f;
  const float mrow = rmax[wv * 16 + sl];
  // PV loop: prefetch next P row (longest dep chain: ds_read->exp->cvt->MFMA)
  f16x8 nraw = *(const f16x8*)(Pw + sl * PT + quad * 8);
  for (int kcc = 0; kcc < NKC; ++kcc) {
    f16x8 raw = nraw;
    if (kcc + 1 < NKC)
      nraw = *(const f16x8*)(Pw + sl * PT + (kcc + 1) * 32 + quad * 8);
    f16x8 ap;
#pragma unroll
    for (int jj = 0; jj < 8; ++jj) {
      float p = __expf((float)raw[jj] - mrow);
      ls += p;
      ap[jj] = (f16)p;
    }
#pragma unroll
    for (int dt = 0; dt < 4; ++dt) {
      const uint32_t* vb =
          (const uint32_t*)(Vt + (dt * 16 + sl) * VT + kcc * 32 + quad * 8);
      union { uint32_t u[4]; f16x8 v; } cv;
      cv.u[0] = vb[0]; cv.u[1] = vb[1]; cv.u[2] = vb[2]; cv.u[3] = vb[3];
      o[dt] = __builtin_amdgcn_mfma_f32_16x16x32_f16(ap, cv.v, o[dt], 0, 0, 0);
    }
  }
  ls += __shfl_xor(ls, 16, 64);
  ls += __shfl_xor(ls, 32, 64);
  if (quad == 0) lsum[wv * 16 + sl] = ls;
  __syncthreads();
#pragma unroll
  for (int r = 0; r < 4; ++r) {
    const int q = quad * 4 + r;
    const float inv = 1.0f / lsum[wv * 16 + q];
    const int grow = i0 + q;
    const int sw = grow & 7;
    f16* yr = y + (((size_t)b * 2048 + grow) << 10) + h * 64;
    const int off = sl & 7, cbase = sl >> 3;
#pragma unroll
    for (int dt = 0; dt < 4; ++dt) {
      int cg = dt * 2 + cbase;
      yr[((cg ^ sw) * 8) + off] = (f16)(o[dt][r] * inv);
    }
  }
}

extern "C" void kernel_launch(void* const* d_in, const int* in_sizes, int n_in,
                              void* d_out, int out_size, void* d_ws,
                              size_t ws_size, hipStream_t stream) {
  (void)in_sizes; (void)n_in; (void)out_size; (void)ws_size;
  const float* x = (const float*)d_in[0];
  const float* Wqkv = (const float*)d_in[1];
  const float* Wproj = (const float*)d_in[2];
  float* out = (float*)d_out;
  char* ws = (char*)d_ws;
  f16* Xh     = (f16*)(ws);                         // 4096x1024 (swizzled)
  f16* WqkvT  = (f16*)(ws + (size_t)8  * 1048576);  // 3072x1024 (swizzled)
  f16* WprojT = (f16*)(ws + (size_t)14 * 1048576);  // 1024x1024 (swizzled)
  f16* QKV    = (f16*)(ws + (size_t)16 * 1048576);  // 4096x3072 (normal)
  f16* Yh     = (f16*)(ws + (size_t)40 * 1048576);  // 4096x1024 (swizzled)

  static bool attr_done = false;
  if (!attr_done) {
    (void)hipFuncSetAttribute((const void*)k_gemm256,
                              hipFuncAttributeMaxDynamicSharedMemorySize,
                              147456);
    attr_done = true;
  }

  k_prep<<<3072, 256, 0, stream>>>(x, Wqkv, Wproj, Xh, WqkvT, WprojT);
  k_gemm256<<<256, 512, 147456, stream>>>(Xh, WqkvT, QKV, 4096, 3072, 1024);
  k_attn<<<1024, 256, 0, stream>>>(QKV, Yh);
  k_gemm_bt<1><<<dim3(32, 8), 256, 0, stream>>>(Yh, WprojT, (void*)out, 4096,
                                                1024, 1024);
}

// Round 6
// 149.778 us; speedup vs baseline: 1.0603x; 1.0517x over previous
//
#include <hip/hip_runtime.h>
#include <cstdint>
#include <cstddef>

typedef _Float16 f16;
typedef f16 f16x2 __attribute__((ext_vector_type(2)));
typedef f16 f16x4 __attribute__((ext_vector_type(4)));
typedef f16 f16x8 __attribute__((ext_vector_type(8)));
typedef float f32x4 __attribute__((ext_vector_type(4)));

// Global layouts for GEMM operands are CHUNK-SWIZZLED: within each 64-f16
// K-group of row r, the 8-f16 chunk c is stored at position c^(r&7).
// GEMM staging is then PURE IDENTITY (load offset == store offset == cid*8);
// fragment reads use the XOR formula (r7-proven conflict-free).

typedef __attribute__((address_space(3))) uint32_t lds_u32_t;
typedef __attribute__((address_space(1))) const uint32_t glb_u32_t;

__device__ __forceinline__ void gload_lds16(const f16* g, f16* l) {
  __builtin_amdgcn_global_load_lds((glb_u32_t*)(uintptr_t)g,
                                   (lds_u32_t*)(uint32_t)(uintptr_t)l,
                                   16, 0, 0);
}

// ---- prep: transposes (0..1023) then x cvt (1024..3071, 8 elems/thread) ----
__global__ __launch_bounds__(256) void k_prep(const float* __restrict__ x,
                                              const float* __restrict__ Wqkv,
                                              const float* __restrict__ Wproj,
                                              f16* __restrict__ Xh,
                                              f16* __restrict__ WqkvT,
                                              f16* __restrict__ WprojT) {
  const int bid = blockIdx.x, t = threadIdx.x;
  if (bid >= 1024) {
    int gid = (bid - 1024) * 256 + t;   // 0..524287
    int r = gid >> 7;                   // row 0..4095
    int c = gid & 127;                  // 8-f16 chunk in row
    int g = c >> 3, cl = c & 7;
    const float* src = x + ((size_t)r << 10) + c * 8;
    float4 u0 = *(const float4*)src;
    float4 u1 = *(const float4*)(src + 4);
    f16x8 hv;
    hv[0] = (f16)u0.x; hv[1] = (f16)u0.y; hv[2] = (f16)u0.z; hv[3] = (f16)u0.w;
    hv[4] = (f16)u1.x; hv[5] = (f16)u1.y; hv[6] = (f16)u1.z; hv[7] = (f16)u1.w;
    *(f16x8*)(Xh + ((size_t)r << 10) + g * 64 + ((cl ^ (r & 7)) * 8)) = hv;
    return;
  }
  const float* in;
  f16* out;
  int N, bx, by;
  if (bid < 768) {
    bx = bid % 48; by = bid / 48; in = Wqkv; out = WqkvT; N = 3072;
  } else {
    int tb = bid - 768;
    bx = tb % 16; by = tb / 16; in = Wproj; out = WprojT; N = 1024;
  }
  const int K = 1024;
  __shared__ float tile[64][65];
  const int xx = t & 63, y0 = t >> 6;
#pragma unroll
  for (int r = 0; r < 16; ++r) {
    int y = y0 + r * 4;
    tile[y][xx] = in[(size_t)(by * 64 + y) * N + bx * 64 + xx];
  }
  __syncthreads();
  const int ch = xx >> 3, off = xx & 7;
#pragma unroll
  for (int r = 0; r < 16; ++r) {
    int y = y0 + r * 4;
    int n = bx * 64 + y;
    out[(size_t)n * K + by * 64 + ((ch ^ (n & 7)) * 8) + off] =
        (f16)tile[xx][y];
  }
}

// ===================== 256x192 deep-pipelined GEMM (QKV) ====================
// r3-proven 2-phase schedule. Counted-vmcnt pipeline: stages for tile t+2
// issued at tile t, vmcnt(7) forces tile t+1 landed; never drain-0 in
// steady state.
__global__ __launch_bounds__(512, 1) void k_gemm256(const f16* __restrict__ A,
                                                    const f16* __restrict__ Bt,
                                                    f16* __restrict__ C,
                                                    int M, int N, int K) {
  extern __shared__ __align__(16) f16 sm[];
  const int t = threadIdx.x;
  const int bid = blockIdx.x;
  const int swz = (bid & 7) * 32 + (bid >> 3);             // 256 = 8 XCD x 32
  const int m0 = (swz & 15) * 256, n0 = (swz >> 4) * 192;
  const int w = t >> 6, l = t & 63, sl = l & 15, quad = l >> 4;
  const int wr = w >> 2, wc = w & 3;                       // 2 x 4 waves
  const f16* Ab = A + (size_t)m0 * K;
  const f16* Bb = Bt + (size_t)n0 * K;
  const int nk = K >> 6;                                   // 16
  f32x4 acc[8][3] = {};
  f16x8 bcur[3][2], bnext[3][2];

  auto abuf = [&](int buf) -> f16* { return sm + buf * 16384; };      // 3x
  auto bbuf = [&](int buf) -> f16* { return sm + 49152 + buf * 12288; }; // 2x

  auto stageA = [&](int kt, int buf) {
    f16* dst = abuf(buf);
#pragma unroll
    for (int c = 0; c < 4; ++c) {
      int cid = t + c * 512, row = cid >> 3;               // row 0..255
      gload_lds16(Ab + (size_t)row * K + kt * 64 + (cid & 7) * 8,
                  dst + cid * 8);
    }
  };
  auto stageB = [&](int kt, int buf) {
    f16* dst = bbuf(buf);
#pragma unroll
    for (int c = 0; c < 3; ++c) {
      int cid = t + c * 512, row = cid >> 3;               // row 0..191
      gload_lds16(Bb + (size_t)row * K + kt * 64 + (cid & 7) * 8,
                  dst + cid * 8);
    }
  };

  // ---- prologue: stage tiles 0,1; force tile0 landed; preload B(0) frags
  stageA(0, 0); stageB(0, 0);
  stageA(1, 1); stageB(1, 1);
  asm volatile("s_waitcnt vmcnt(7)" ::: "memory");   // oldest 7 = tile0's
  __builtin_amdgcn_sched_barrier(0);
  __builtin_amdgcn_s_barrier();
#pragma unroll
  for (int ni = 0; ni < 3; ++ni) {
    const int rb = wc * 48 + ni * 16 + sl;
#pragma unroll
    for (int kx = 0; kx < 2; ++kx)
      bcur[ni][kx] = *(const f16x8*)(bbuf(0) + rb * 64 +
                                     (((kx * 4 + quad) ^ (rb & 7)) * 8));
  }
  asm volatile("s_waitcnt lgkmcnt(0)" ::: "memory");
  __builtin_amdgcn_sched_barrier(0);
  __builtin_amdgcn_s_barrier();                      // B(0) reads retired

  int ba = 0;                                        // A buffer = kt % 3
  for (int kt = 0; kt < nk; ++kt) {
    const int bb = kt & 1;
    const int ba2 = ba + 2 >= 3 ? ba - 1 : ba + 2;   // (kt+2) % 3
    const int ban = ba + 1 >= 3 ? 0 : ba + 1;        // (kt+1) % 3
    // ---------------- PH1: stage t+2, JIT A0-3, MFMA mi0-3 ----------------
    if (kt + 2 < nk) { stageA(kt + 2, ba2); stageB(kt + 2, bb); }
    f16x8 afl[4][2];
#pragma unroll
    for (int mi = 0; mi < 4; ++mi) {
      const int ra = wr * 128 + mi * 16 + sl;
#pragma unroll
      for (int kx = 0; kx < 2; ++kx)
        afl[mi][kx] = *(const f16x8*)(abuf(ba) + ra * 64 +
                                      (((kx * 4 + quad) ^ (ra & 7)) * 8));
    }
    __builtin_amdgcn_s_setprio(1);
#pragma unroll
    for (int mi = 0; mi < 4; ++mi)
#pragma unroll
      for (int ni = 0; ni < 3; ++ni)
#pragma unroll
        for (int kx = 0; kx < 2; ++kx)
          acc[mi][ni] = __builtin_amdgcn_mfma_f32_16x16x32_f16(
              afl[mi][kx], bcur[ni][kx], acc[mi][ni], 0, 0, 0);
    __builtin_amdgcn_s_setprio(0);
    if (kt + 2 < nk)
      asm volatile("s_waitcnt vmcnt(7)" ::: "memory");  // forces tile t+1
    else
      asm volatile("s_waitcnt vmcnt(0)" ::: "memory");  // tail: drain
    __builtin_amdgcn_sched_barrier(0);
    __builtin_amdgcn_s_barrier();
    // ------------- PH2: A4-7 + B(t+1) reads, MFMA mi4-7, WAR fence --------
    f16x8 afh[4][2];
#pragma unroll
    for (int mi = 0; mi < 4; ++mi) {
      const int ra = wr * 128 + (mi + 4) * 16 + sl;
#pragma unroll
      for (int kx = 0; kx < 2; ++kx)
        afh[mi][kx] = *(const f16x8*)(abuf(ba) + ra * 64 +
                                      (((kx * 4 + quad) ^ (ra & 7)) * 8));
    }
    if (kt + 1 < nk) {
#pragma unroll
      for (int ni = 0; ni < 3; ++ni) {
        const int rb = wc * 48 + ni * 16 + sl;
#pragma unroll
        for (int kx = 0; kx < 2; ++kx)
          bnext[ni][kx] = *(const f16x8*)(bbuf((kt + 1) & 1) + rb * 64 +
                                          (((kx * 4 + quad) ^ (rb & 7)) * 8));
      }
    }
    __builtin_amdgcn_s_setprio(1);
#pragma unroll
    for (int mi = 0; mi < 4; ++mi)
#pragma unroll
      for (int ni = 0; ni < 3; ++ni)
#pragma unroll
        for (int kx = 0; kx < 2; ++kx)
          acc[mi + 4][ni] = __builtin_amdgcn_mfma_f32_16x16x32_f16(
              afh[mi][kx], bcur[ni][kx], acc[mi + 4][ni], 0, 0, 0);
    __builtin_amdgcn_s_setprio(0);
    asm volatile("s_waitcnt lgkmcnt(0)" ::: "memory");  // all reads retired
    __builtin_amdgcn_sched_barrier(0);
    __builtin_amdgcn_s_barrier();                       // restage-safe
#pragma unroll
    for (int ni = 0; ni < 3; ++ni)
#pragma unroll
      for (int kx = 0; kx < 2; ++kx)
        bcur[ni][kx] = bnext[ni][kx];
    ba = ban;
  }
  // ---- epilogue: C write (f16) ----
#pragma unroll
  for (int mi = 0; mi < 8; ++mi)
#pragma unroll
    for (int ni = 0; ni < 3; ++ni) {
      const int row = m0 + wr * 128 + mi * 16 + quad * 4;
      const int col = n0 + wc * 48 + ni * 16 + sl;
#pragma unroll
      for (int r = 0; r < 4; ++r)
        C[(size_t)(row + r) * N + col] = (f16)acc[mi][ni][r];
    }
}

// ============ 128x128 pipelined GEMM (proj) — r3 schedule at 128² ==========
// 256 thr / 4 waves (2x2, 64x64 each). A: 3 bufs, B: 2 bufs (80 KiB ->
// 2 blocks/CU). stage(t+2) at iter t; vmcnt(8) (= t+2's 8 loads in flight)
// forces t+1 landed; B(t+1) frags pre-read in PH2; lgkm0+barrier WAR fence.
template <int F32OUT>
__global__ __launch_bounds__(256, 2) void k_gemm128p(const f16* __restrict__ A,
                                                     const f16* __restrict__ Bt,
                                                     void* __restrict__ Cout,
                                                     int M, int N, int K) {
  extern __shared__ __align__(16) f16 sm[];
  const int t = threadIdx.x;
  const int m0 = blockIdx.x * 128, n0 = blockIdx.y * 128;
  const int w = t >> 6, l = t & 63, sl = l & 15, quad = l >> 4;
  const int wm = (w & 1) * 64, wn = (w >> 1) * 64;
  const f16* Ab = A + (size_t)m0 * K;
  const f16* Bb = Bt + (size_t)n0 * K;
  const int nk = K >> 6;                                   // 16
  f32x4 acc[4][4] = {};
  f16x8 bcur[4][2], bnext[4][2];

  auto abuf = [&](int buf) -> f16* { return sm + buf * 8192; };        // 3x
  auto bbuf = [&](int buf) -> f16* { return sm + 24576 + buf * 8192; };// 2x

  auto stageA = [&](int kt, int buf) {
    f16* dst = abuf(buf);
#pragma unroll
    for (int c = 0; c < 4; ++c) {
      int cid = t + c * 256, row = cid >> 3;               // row 0..127
      gload_lds16(Ab + (size_t)row * K + kt * 64 + (cid & 7) * 8,
                  dst + cid * 8);
    }
  };
  auto stageB = [&](int kt, int buf) {
    f16* dst = bbuf(buf);
#pragma unroll
    for (int c = 0; c < 4; ++c) {
      int cid = t + c * 256, row = cid >> 3;               // row 0..127
      gload_lds16(Bb + (size_t)row * K + kt * 64 + (cid & 7) * 8,
                  dst + cid * 8);
    }
  };

  // ---- prologue: stage tiles 0,1; force tile0 landed; preload B(0) frags
  stageA(0, 0); stageB(0, 0);
  stageA(1, 1); stageB(1, 1);
  asm volatile("s_waitcnt vmcnt(8)" ::: "memory");   // tile0's 8 landed
  __builtin_amdgcn_sched_barrier(0);
  __builtin_amdgcn_s_barrier();
#pragma unroll
  for (int ni = 0; ni < 4; ++ni) {
    const int rb = wn + ni * 16 + sl;
#pragma unroll
    for (int kx = 0; kx < 2; ++kx)
      bcur[ni][kx] = *(const f16x8*)(bbuf(0) + rb * 64 +
                                     (((kx * 4 + quad) ^ (rb & 7)) * 8));
  }
  asm volatile("s_waitcnt lgkmcnt(0)" ::: "memory");
  __builtin_amdgcn_sched_barrier(0);
  __builtin_amdgcn_s_barrier();                      // B(0) reads retired

  int ba = 0;                                        // A buffer = kt % 3
  for (int kt = 0; kt < nk; ++kt) {
    const int bb = kt & 1;
    const int ba2 = ba + 2 >= 3 ? ba - 1 : ba + 2;   // (kt+2) % 3
    const int ban = ba + 1 >= 3 ? 0 : ba + 1;        // (kt+1) % 3
    // ---------------- PH1: stage t+2, JIT A kx=0, MFMA kx=0 ----------------
    if (kt + 2 < nk) { stageA(kt + 2, ba2); stageB(kt + 2, bb); }
    f16x8 af[4];
#pragma unroll
    for (int mi = 0; mi < 4; ++mi) {
      const int ra = wm + mi * 16 + sl;
      af[mi] = *(const f16x8*)(abuf(ba) + ra * 64 +
                               ((quad ^ (ra & 7)) * 8));
    }
    __builtin_amdgcn_s_setprio(1);
#pragma unroll
    for (int mi = 0; mi < 4; ++mi)
#pragma unroll
      for (int ni = 0; ni < 4; ++ni)
        acc[mi][ni] = __builtin_amdgcn_mfma_f32_16x16x32_f16(
            af[mi], bcur[ni][0], acc[mi][ni], 0, 0, 0);
    __builtin_amdgcn_s_setprio(0);
    if (kt + 2 < nk)
      asm volatile("s_waitcnt vmcnt(8)" ::: "memory");  // forces tile t+1
    else
      asm volatile("s_waitcnt vmcnt(0)" ::: "memory");  // tail: drain
    __builtin_amdgcn_sched_barrier(0);
    __builtin_amdgcn_s_barrier();
    // ------------- PH2: A kx=1 + B(t+1) reads, MFMA kx=1, WAR fence --------
    f16x8 af2[4];
#pragma unroll
    for (int mi = 0; mi < 4; ++mi) {
      const int ra = wm + mi * 16 + sl;
      af2[mi] = *(const f16x8*)(abuf(ba) + ra * 64 +
                                (((4 + quad) ^ (ra & 7)) * 8));
    }
    if (kt + 1 < nk) {
#pragma unroll
      for (int ni = 0; ni < 4; ++ni) {
        const int rb = wn + ni * 16 + sl;
#pragma unroll
        for (int kx = 0; kx < 2; ++kx)
          bnext[ni][kx] = *(const f16x8*)(bbuf((kt + 1) & 1) + rb * 64 +
                                          (((kx * 4 + quad) ^ (rb & 7)) * 8));
      }
    }
    __builtin_amdgcn_s_setprio(1);
#pragma unroll
    for (int mi = 0; mi < 4; ++mi)
#pragma unroll
      for (int ni = 0; ni < 4; ++ni)
        acc[mi][ni] = __builtin_amdgcn_mfma_f32_16x16x32_f16(
            af2[mi], bcur[ni][1], acc[mi][ni], 0, 0, 0);
    __builtin_amdgcn_s_setprio(0);
    asm volatile("s_waitcnt lgkmcnt(0)" ::: "memory");  // all reads retired
    __builtin_amdgcn_sched_barrier(0);
    __builtin_amdgcn_s_barrier();                       // restage-safe
#pragma unroll
    for (int ni = 0; ni < 4; ++ni)
#pragma unroll
      for (int kx = 0; kx < 2; ++kx)
        bcur[ni][kx] = bnext[ni][kx];
    ba = ban;
  }
  // ---- epilogue ----
#pragma unroll
  for (int mi = 0; mi < 4; ++mi)
#pragma unroll
    for (int ni = 0; ni < 4; ++ni) {
      int row = m0 + wm + mi * 16 + quad * 4;
      int col = n0 + wn + ni * 16 + sl;
#pragma unroll
      for (int r = 0; r < 4; ++r) {
        if (F32OUT)
          ((float*)Cout)[(size_t)(row + r) * N + col] = acc[mi][ni][r];
        else
          ((f16*)Cout)[(size_t)(row + r) * N + col] = (f16)acc[mi][ni][r];
      }
    }
}

// ---------------- MFMA sparse flash attention (r12 version) ----------------
__global__ __launch_bounds__(256) void k_attn(const f16* __restrict__ qkv,
                                              f16* __restrict__ y) {
  constexpr int VT = 226;
  constexpr int KT = 72;
  constexpr int PT = 232;
  __shared__ __align__(16) char smem[224 * KT * 2 + 4 * 16 * PT * 2 + 512];
  f16* Ks = (f16*)smem;
  f16* Vt = (f16*)smem;                  // aliases Ks (phase 3+)
  f16* Pb = (f16*)(smem + 224 * KT * 2);
  float* rmax = (float*)(smem + 224 * KT * 2 + 4 * 16 * PT * 2);
  float* lsum = rmax + 64;

  const int t = threadIdx.x, wv = t >> 6, l = t & 63;
  const int sl = l & 15, quad = l >> 4;
  const int blk = blockIdx.x;
  const int qb = blk & 31;
  const int bh = blk >> 5;
  const int b = bh >> 4, h = bh & 15;
  const f16* base = qkv + (size_t)b * 2048 * 3072;
  const int qc = h * 64, kc = 1024 + h * 64, vc = 2048 + h * 64;

  const int row0 = qb * 64;
  const int hi = row0 + 63;
  int lo = row0 - 127; if (lo < 0) lo = 0;
  const int ng = (lo + 63) >> 6;
  const int T = ng + (hi - lo + 1);
  int NT = (T + 15) >> 4;
  NT = (NT + 1) & ~1;
  const int NC = NT * 16;

  for (int cid = t; cid < NC * 8; cid += 256) {
    int idx = cid >> 3, ch = cid & 7;
    int j = idx < ng ? idx * 64 : lo + idx - ng;
    if (idx >= T) j = lo;
    *(uint4*)(Ks + idx * KT + ch * 8) =
        *(const uint4*)(base + (size_t)j * 3072 + kc + ch * 8);
  }
  const int i0 = row0 + wv * 16;
  f16x8 aq[2];
#pragma unroll
  for (int c = 0; c < 2; ++c) {
    f16x8 qv = *(const f16x8*)(base + (size_t)(i0 + sl) * 3072 + qc + c * 32 +
                               quad * 8);
#pragma unroll
    for (int jj = 0; jj < 8; ++jj) qv[jj] = qv[jj] * (f16)0.125f;
    aq[c] = qv;
  }
  __syncthreads();

  f16* Pw = Pb + wv * 16 * PT;
  float mloc[4] = {-INFINITY, -INFINITY, -INFINITY, -INFINITY};
  for (int kt = 0; kt < NT; ++kt) {
    const int idx = kt * 16 + sl;
    const bool pad = idx >= T;
    int j = idx < ng ? idx * 64 : lo + idx - ng;
    if (pad) j = lo;
    const f16* krow = Ks + idx * KT;
    f16x8 bk0 = *(const f16x8*)(krow + quad * 8);
    f16x8 bk1 = *(const f16x8*)(krow + 32 + quad * 8);
    f32x4 s = {0.f, 0.f, 0.f, 0.f};
    s = __builtin_amdgcn_mfma_f32_16x16x32_f16(aq[0], bk0, s, 0, 0, 0);
    s = __builtin_amdgcn_mfma_f32_16x16x32_f16(aq[1], bk1, s, 0, 0, 0);
#pragma unroll
    for (int r = 0; r < 4; ++r) {
      const int i = i0 + quad * 4 + r;
      const bool ok = !pad && (j <= i) && ((i - j) < 128 || (j & 63) == 0);
      const float sv = ok ? s[r] : -INFINITY;
      mloc[r] = fmaxf(mloc[r], sv);
      Pw[(quad * 4 + r) * PT + idx] = (f16)sv;
    }
  }
#pragma unroll
  for (int off = 1; off < 16; off <<= 1)
#pragma unroll
    for (int r = 0; r < 4; ++r)
      mloc[r] = fmaxf(mloc[r], __shfl_xor(mloc[r], off, 64));
  if (sl == 0)
#pragma unroll
    for (int r = 0; r < 4; ++r) rmax[wv * 16 + quad * 4 + r] = mloc[r];
  __syncthreads();

  for (int cid = t; cid < NC * 8; cid += 256) {
    int idx = cid >> 3, ch = cid & 7;
    int j = idx < ng ? idx * 64 : lo + idx - ng;
    if (idx >= T) j = lo;
    f16x8 v8 = *(const f16x8*)(base + (size_t)j * 3072 + vc + ch * 8);
#pragma unroll
    for (int jj = 0; jj < 8; ++jj) Vt[(ch * 8 + jj) * VT + idx] = v8[jj];
  }
  __syncthreads();

  const int NKC = NC / 32;
  f32x4 o[4] = {};
  float ls = 0.f;
  const float mrow = rmax[wv * 16 + sl];
  for (int kcc = 0; kcc < NKC; ++kcc) {
    f16x8 raw = *(const f16x8*)(Pw + sl * PT + kcc * 32 + quad * 8);
    f16x8 ap;
#pragma unroll
    for (int jj = 0; jj < 8; ++jj) {
      float p = __expf((float)raw[jj] - mrow);
      ls += p;
      ap[jj] = (f16)p;
    }
#pragma unroll
    for (int dt = 0; dt < 4; ++dt) {
      const uint32_t* vb =
          (const uint32_t*)(Vt + (dt * 16 + sl) * VT + kcc * 32 + quad * 8);
      union { uint32_t u[4]; f16x8 v; } cv;
      cv.u[0] = vb[0]; cv.u[1] = vb[1]; cv.u[2] = vb[2]; cv.u[3] = vb[3];
      o[dt] = __builtin_amdgcn_mfma_f32_16x16x32_f16(ap, cv.v, o[dt], 0, 0, 0);
    }
  }
  ls += __shfl_xor(ls, 16, 64);
  ls += __shfl_xor(ls, 32, 64);
  if (quad == 0) lsum[wv * 16 + sl] = ls;
  __syncthreads();
#pragma unroll
  for (int r = 0; r < 4; ++r) {
    const int q = quad * 4 + r;
    const float inv = 1.0f / lsum[wv * 16 + q];
    const int grow = i0 + q;
    const int sw = grow & 7;
    f16* yr = y + (((size_t)b * 2048 + grow) << 10) + h * 64;
    const int off = sl & 7, cbase = sl >> 3;
#pragma unroll
    for (int dt = 0; dt < 4; ++dt) {
      int cg = dt * 2 + cbase;
      yr[((cg ^ sw) * 8) + off] = (f16)(o[dt][r] * inv);
    }
  }
}

extern "C" void kernel_launch(void* const* d_in, const int* in_sizes, int n_in,
                              void* d_out, int out_size, void* d_ws,
                              size_t ws_size, hipStream_t stream) {
  (void)in_sizes; (void)n_in; (void)out_size; (void)ws_size;
  const float* x = (const float*)d_in[0];
  const float* Wqkv = (const float*)d_in[1];
  const float* Wproj = (const float*)d_in[2];
  float* out = (float*)d_out;
  char* ws = (char*)d_ws;
  f16* Xh     = (f16*)(ws);                         // 4096x1024 (swizzled)
  f16* WqkvT  = (f16*)(ws + (size_t)8  * 1048576);  // 3072x1024 (swizzled)
  f16* WprojT = (f16*)(ws + (size_t)14 * 1048576);  // 1024x1024 (swizzled)
  f16* QKV    = (f16*)(ws + (size_t)16 * 1048576);  // 4096x3072 (normal)
  f16* Yh     = (f16*)(ws + (size_t)40 * 1048576);  // 4096x1024 (swizzled)

  static bool attr_done = false;
  if (!attr_done) {
    (void)hipFuncSetAttribute((const void*)k_gemm256,
                              hipFuncAttributeMaxDynamicSharedMemorySize,
                              147456);
    (void)hipFuncSetAttribute((const void*)k_gemm128p<1>,
                              hipFuncAttributeMaxDynamicSharedMemorySize,
                              81920);
    attr_done = true;
  }

  k_prep<<<3072, 256, 0, stream>>>(x, Wqkv, Wproj, Xh, WqkvT, WprojT);
  k_gemm256<<<256, 512, 147456, stream>>>(Xh, WqkvT, QKV, 4096, 3072, 1024);
  k_attn<<<1024, 256, 0, stream>>>(QKV, Yh);
  k_gemm128p<1><<<dim3(32, 8), 256, 81920, stream>>>(Yh, WprojT, (void*)out,
                                                     4096, 1024, 1024);
}